// Round 5
// baseline (117.882 us; speedup 1.0000x reference)
//
#include <hip/hip_runtime.h>

// Problem constants
#define V 8
#define B 32
#define CIN 8
#define T 4096
#define O 64
#define K 5
#define H 16

// Padded xs row: [0..3]=0, data at [4..4099], [4100..4103]=0.
// conv(t) = sum_j w[j]*xs[t+j-2] = sum_j w[j]*xs_pad[t+j+2]
#define XSTRIDE 4104

// workspace layout (floats)
#define XS_OFF 0
#define S_OFF  (V*B*XSTRIDE)          // xs: 256 rows * 4104
#define SM_OFF (S_OFF + V*B*O)        // s means; sm follows
// sm size: B*64

typedef float floatx4 __attribute__((ext_vector_type(4)));

__device__ __forceinline__ float selu_f(float x) {
    const float SC = 1.0507009873554805f;
    const float SA = 1.7580993408473766f;  // scale*alpha
    float e = __expf(x);
    float neg = SA * e - SA;               // scale*alpha*(exp(x)-1)
    return x > 0.0f ? SC * x : neg;
}

__device__ __forceinline__ float sload(const float* p) {
    // force block-uniform value into SGPR
    return __int_as_float(__builtin_amdgcn_readfirstlane(__float_as_int(*p)));
}

// K01: xs row build (LDS + global) + per-(row,o) mean of selu(conv).
// grid = V*B (=256), block = 512 (8 waves).
__global__ __launch_bounds__(512) void k_xs_mean(
        const float* __restrict__ x, const float* __restrict__ cw,
        const float* __restrict__ cb, float* __restrict__ ws,
        float* __restrict__ s_out) {
    int row = blockIdx.x;                  // v*B + b
    int tid = threadIdx.x;
    __shared__ float xsh[XSTRIDE];
    const float* xr = x + (size_t)row * CIN * T;
    float* xp = ws + XS_OFF + (size_t)row * XSTRIDE;

    // Phase 1: xs = sum_c x[..c..], 8 t's per thread, float4 I/O.
    {
        int t0 = tid * 8;
        float4 a0 = make_float4(0.f, 0.f, 0.f, 0.f);
        float4 a1 = make_float4(0.f, 0.f, 0.f, 0.f);
        #pragma unroll
        for (int c = 0; c < CIN; ++c) {
            const float4* q = (const float4*)(xr + c * T + t0);
            float4 u = q[0], v2 = q[1];
            a0.x += u.x; a0.y += u.y; a0.z += u.z; a0.w += u.w;
            a1.x += v2.x; a1.y += v2.y; a1.z += v2.z; a1.w += v2.w;
        }
        *(float4*)(&xsh[t0 + 4]) = a0;
        *(float4*)(&xsh[t0 + 8]) = a1;
        *(float4*)(xp + t0 + 4) = a0;
        *(float4*)(xp + t0 + 8) = a1;
        if (tid < 4) {
            xsh[tid] = 0.0f; xsh[4100 + tid] = 0.0f;
            xp[tid] = 0.0f;  xp[4100 + tid] = 0.0f;
        }
    }
    __syncthreads();

    // Phase 2: mean_t selu(conv). lane = o (broadcast LDS reads), wave = t-chunk.
    int wave = tid >> 6;
    int lane = tid & 63;                   // = o
    float w0 = cw[lane * 5 + 0], w1 = cw[lane * 5 + 1], w2 = cw[lane * 5 + 2];
    float w3 = cw[lane * 5 + 3], w4 = cw[lane * 5 + 4];
    float bv = cb[lane];
    int c0 = wave * 512;
    float a0 = xsh[c0 + 2], a1 = xsh[c0 + 3], a2 = xsh[c0 + 4], a3 = xsh[c0 + 5];
    float acc = 0.0f;
    #pragma unroll 8
    for (int t = c0; t < c0 + 512; ++t) {
        float a4 = xsh[t + 6];
        float cv = bv + w0 * a0 + w1 * a1 + w2 * a2 + w3 * a3 + w4 * a4;
        acc += selu_f(cv);
        a0 = a1; a1 = a2; a2 = a3; a3 = a4;
    }
    __shared__ float part[8][64];
    part[wave][lane] = acc;
    __syncthreads();
    if (tid < 64) {
        float tot = 0.0f;
        #pragma unroll
        for (int w = 0; w < 8; ++w) tot += part[w][tid];
        s_out[row * 64 + tid] = tot * (1.0f / (float)T);
    }
}

// K23: SE MLP -> gate -> compressed -> af/at -> softmax sm.
// grid = B (=32), block = 512: wave = v, lane = o.
__global__ __launch_bounds__(512) void k_se_sm(
        const float* __restrict__ s_in, const float* __restrict__ w1,
        const float* __restrict__ b1, const float* __restrict__ w2,
        const float* __restrict__ b2, const float* __restrict__ awv,
        float* __restrict__ sm) {
    int b = blockIdx.x;
    int tid = threadIdx.x;
    int v = tid >> 6;
    int o = tid & 63;
    __shared__ float ssh[8][64];
    __shared__ float hsh[8][16];
    __shared__ float afs[8], ats[8];
    float so = s_in[(v * B + b) * 64 + o];
    ssh[v][o] = so;
    __syncthreads();
    if (o < 16) {
        float hv = b1[v * 16 + o];
        #pragma unroll
        for (int j = 0; j < 64; ++j) hv += ssh[v][j] * w1[(v * 16 + o) * 64 + j];
        hsh[v][o] = fmaxf(hv, 0.0f);
    }
    __syncthreads();
    float gv = b2[v * 64 + o];
    #pragma unroll
    for (int j = 0; j < 16; ++j) gv += hsh[v][j] * w2[(v * 64 + o) * 16 + j];
    float gate = 1.0f / (1.0f + __expf(-gv));
    float comp = so * gate;
    float pf = comp * awv[o];
    float pt = comp * awv[64 + o];
    #pragma unroll
    for (int m = 32; m >= 1; m >>= 1) {
        pf += __shfl_xor(pf, m, 64);
        pt += __shfl_xor(pt, m, 64);
    }
    if (o == 0) { afs[v] = pf; ats[v] = pt; }
    __syncthreads();
    if (tid < 64) {
        int f = tid >> 3, g = tid & 7;
        float a = selu_f(afs[f] + ats[g]);
        float m = a;
        m = fmaxf(m, __shfl_xor(m, 8, 64));
        m = fmaxf(m, __shfl_xor(m, 16, 64));
        m = fmaxf(m, __shfl_xor(m, 32, 64));
        float e = __expf(a - m);
        float ssum = e;
        ssum += __shfl_xor(ssum, 8, 64);
        ssum += __shfl_xor(ssum, 16, 64);
        ssum += __shfl_xor(ssum, 32, 64);
        sm[b * 64 + tid] = e / ssum;       // layout [b][f*8+g]
    }
}

// K4: out[g,b,o,t] = sum_f sm[f,g,b]*selu(conv[f,b,o,t]), conv recomputed.
// grid = B * 4 tiles * 4 og = 512 blocks, block=256. Thread owns (b, 4 t's), 16 o's.
// Output stores are NONTEMPORAL: out is write-once/never-read; bypassing L2/L3
// keeps xs + weights resident so the 4x-redundant xs window reads stay L2 hits.
__global__ __launch_bounds__(256) void k_out(
        const float* __restrict__ ws, const float* __restrict__ cw,
        const float* __restrict__ cb, float* __restrict__ out) {
    int blk = blockIdx.x;
    int b = blk >> 4;                      // 0..31
    int r = blk & 15;
    int tile = r >> 2;                     // 0..3
    int og = r & 3;                        // 0..3
    int t0 = tile * 1024 + threadIdx.x * 4;

    // softmax weights: block-uniform -> SGPRs
    const float* smp = ws + SM_OFF + b * 64;
    float smv[64];
    #pragma unroll
    for (int i = 0; i < 64; ++i) smv[i] = sload(smp + i);

    // xs windows: xw[f][k] = xs_pad[t0+2+k], k=0..7 (covers 4 outputs, K=5)
    float xw[8][8];
    #pragma unroll
    for (int f = 0; f < 8; ++f) {
        const float* xp = ws + XS_OFF + (size_t)(f * B + b) * XSTRIDE + t0;
        float4 q0 = *(const float4*)(xp);
        float4 q1 = *(const float4*)(xp + 4);
        float4 q2 = *(const float4*)(xp + 8);
        xw[f][0] = q0.z; xw[f][1] = q0.w;
        xw[f][2] = q1.x; xw[f][3] = q1.y; xw[f][4] = q1.z; xw[f][5] = q1.w;
        xw[f][6] = q2.x; xw[f][7] = q2.y;
    }

    #pragma unroll 1
    for (int oi = 0; oi < 16; ++oi) {
        int o = og * 16 + oi;
        float w0 = sload(cw + o * 5 + 0), w1 = sload(cw + o * 5 + 1);
        float w2 = sload(cw + o * 5 + 2), w3 = sload(cw + o * 5 + 3);
        float w4 = sload(cw + o * 5 + 4);
        float bv = sload(cb + o);
        float acc[8][4];
        #pragma unroll
        for (int g = 0; g < 8; ++g)
            #pragma unroll
            for (int dt = 0; dt < 4; ++dt) acc[g][dt] = 0.0f;
        #pragma unroll
        for (int f = 0; f < 8; ++f) {
            float cv[4];
            #pragma unroll
            for (int dt = 0; dt < 4; ++dt) {
                float c = bv + w0 * xw[f][dt] + w1 * xw[f][dt + 1] + w2 * xw[f][dt + 2]
                             + w3 * xw[f][dt + 3] + w4 * xw[f][dt + 4];
                cv[dt] = selu_f(c);
            }
            #pragma unroll
            for (int g = 0; g < 8; ++g) {
                float s = smv[f * 8 + g];
                #pragma unroll
                for (int dt = 0; dt < 4; ++dt) acc[g][dt] += s * cv[dt];
            }
        }
        #pragma unroll
        for (int g = 0; g < 8; ++g) {
            floatx4 o4 = {acc[g][0], acc[g][1], acc[g][2], acc[g][3]};
            floatx4* dst = (floatx4*)(out + ((size_t)(g * B + b) * O + o) * T + t0);
            __builtin_nontemporal_store(o4, dst);
        }
    }
}

extern "C" void kernel_launch(void* const* d_in, const int* in_sizes, int n_in,
                              void* d_out, int out_size, void* d_ws, size_t ws_size,
                              hipStream_t stream) {
    const float* x      = (const float*)d_in[0];
    const float* conv_w = (const float*)d_in[1];
    const float* conv_b = (const float*)d_in[2];
    const float* se_w1  = (const float*)d_in[3];
    const float* se_b1  = (const float*)d_in[4];
    const float* se_w2  = (const float*)d_in[5];
    const float* se_b2  = (const float*)d_in[6];
    const float* attn_w = (const float*)d_in[7];
    float* out = (float*)d_out;
    float* ws  = (float*)d_ws;

    k_xs_mean<<<V * B, 512, 0, stream>>>(x, conv_w, conv_b, ws, ws + S_OFF);
    k_se_sm<<<B, 512, 0, stream>>>(ws + S_OFF, se_w1, se_b1, se_w2, se_b2, attn_w,
                                   ws + SM_OFF);
    k_out<<<B * 4 * 4, 256, 0, stream>>>(ws, conv_w, conv_b, out);
}

// Round 6
// 113.748 us; speedup vs baseline: 1.0363x; 1.0363x over previous
//
#include <hip/hip_runtime.h>

// Problem constants
#define V 8
#define B 32
#define CIN 8
#define T 4096
#define O 64
#define K 5
#define H 16

// Padded xs row: [0..3]=0, data at [4..4099], [4100..4103]=0.
// conv(t) = sum_j w[j]*xs[t+j-2] = sum_j w[j]*xs_pad[t+j+2]
#define XSTRIDE 4104

// workspace layout (floats)
#define XS_OFF 0
#define S_OFF  (V*B*XSTRIDE)          // xs: 256 rows * 4104
#define SM_OFF (S_OFF + V*B*O)        // s means; sm follows
// sm size: B*64

__device__ __forceinline__ float selu_f(float x) {
    const float SC = 1.0507009873554805f;
    const float SA = 1.7580993408473766f;  // scale*alpha
    float e = __expf(x);
    float neg = SA * e - SA;               // scale*alpha*(exp(x)-1)
    return x > 0.0f ? SC * x : neg;
}

__device__ __forceinline__ float sload(const float* p) {
    // force block-uniform value into SGPR
    return __int_as_float(__builtin_amdgcn_readfirstlane(__float_as_int(*p)));
}

// K01: xs row build (LDS + global) + per-(row,o) mean of selu(conv).
// grid = V*B (=256), block = 512 (8 waves).
__global__ __launch_bounds__(512) void k_xs_mean(
        const float* __restrict__ x, const float* __restrict__ cw,
        const float* __restrict__ cb, float* __restrict__ ws,
        float* __restrict__ s_out) {
    int row = blockIdx.x;                  // v*B + b
    int tid = threadIdx.x;
    __shared__ float xsh[XSTRIDE];
    const float* xr = x + (size_t)row * CIN * T;
    float* xp = ws + XS_OFF + (size_t)row * XSTRIDE;

    // Phase 1: xs = sum_c x[..c..], 8 t's per thread, float4 I/O.
    {
        int t0 = tid * 8;
        float4 a0 = make_float4(0.f, 0.f, 0.f, 0.f);
        float4 a1 = make_float4(0.f, 0.f, 0.f, 0.f);
        #pragma unroll
        for (int c = 0; c < CIN; ++c) {
            const float4* q = (const float4*)(xr + c * T + t0);
            float4 u = q[0], v2 = q[1];
            a0.x += u.x; a0.y += u.y; a0.z += u.z; a0.w += u.w;
            a1.x += v2.x; a1.y += v2.y; a1.z += v2.z; a1.w += v2.w;
        }
        *(float4*)(&xsh[t0 + 4]) = a0;
        *(float4*)(&xsh[t0 + 8]) = a1;
        *(float4*)(xp + t0 + 4) = a0;
        *(float4*)(xp + t0 + 8) = a1;
        if (tid < 4) {
            xsh[tid] = 0.0f; xsh[4100 + tid] = 0.0f;
            xp[tid] = 0.0f;  xp[4100 + tid] = 0.0f;
        }
    }
    __syncthreads();

    // Phase 2: mean_t selu(conv). lane = o (broadcast LDS reads), wave = t-chunk.
    int wave = tid >> 6;
    int lane = tid & 63;                   // = o
    float w0 = cw[lane * 5 + 0], w1 = cw[lane * 5 + 1], w2 = cw[lane * 5 + 2];
    float w3 = cw[lane * 5 + 3], w4 = cw[lane * 5 + 4];
    float bv = cb[lane];
    int c0 = wave * 512;
    float a0 = xsh[c0 + 2], a1 = xsh[c0 + 3], a2 = xsh[c0 + 4], a3 = xsh[c0 + 5];
    float acc = 0.0f;
    #pragma unroll 8
    for (int t = c0; t < c0 + 512; ++t) {
        float a4 = xsh[t + 6];
        float cv = bv + w0 * a0 + w1 * a1 + w2 * a2 + w3 * a3 + w4 * a4;
        acc += selu_f(cv);
        a0 = a1; a1 = a2; a2 = a3; a3 = a4;
    }
    __shared__ float part[8][64];
    part[wave][lane] = acc;
    __syncthreads();
    if (tid < 64) {
        float tot = 0.0f;
        #pragma unroll
        for (int w = 0; w < 8; ++w) tot += part[w][tid];
        s_out[row * 64 + tid] = tot * (1.0f / (float)T);
    }
}

// K23: SE MLP -> gate -> compressed -> af/at -> softmax sm.
// grid = B (=32), block = 512: wave = v, lane = o.
__global__ __launch_bounds__(512) void k_se_sm(
        const float* __restrict__ s_in, const float* __restrict__ w1,
        const float* __restrict__ b1, const float* __restrict__ w2,
        const float* __restrict__ b2, const float* __restrict__ awv,
        float* __restrict__ sm) {
    int b = blockIdx.x;
    int tid = threadIdx.x;
    int v = tid >> 6;
    int o = tid & 63;
    __shared__ float ssh[8][64];
    __shared__ float hsh[8][16];
    __shared__ float afs[8], ats[8];
    float so = s_in[(v * B + b) * 64 + o];
    ssh[v][o] = so;
    __syncthreads();
    if (o < 16) {
        float hv = b1[v * 16 + o];
        #pragma unroll
        for (int j = 0; j < 64; ++j) hv += ssh[v][j] * w1[(v * 16 + o) * 64 + j];
        hsh[v][o] = fmaxf(hv, 0.0f);
    }
    __syncthreads();
    float gv = b2[v * 64 + o];
    #pragma unroll
    for (int j = 0; j < 16; ++j) gv += hsh[v][j] * w2[(v * 64 + o) * 16 + j];
    float gate = 1.0f / (1.0f + __expf(-gv));
    float comp = so * gate;
    float pf = comp * awv[o];
    float pt = comp * awv[64 + o];
    #pragma unroll
    for (int m = 32; m >= 1; m >>= 1) {
        pf += __shfl_xor(pf, m, 64);
        pt += __shfl_xor(pt, m, 64);
    }
    if (o == 0) { afs[v] = pf; ats[v] = pt; }
    __syncthreads();
    if (tid < 64) {
        int f = tid >> 3, g = tid & 7;
        float a = selu_f(afs[f] + ats[g]);
        float m = a;
        m = fmaxf(m, __shfl_xor(m, 8, 64));
        m = fmaxf(m, __shfl_xor(m, 16, 64));
        m = fmaxf(m, __shfl_xor(m, 32, 64));
        float e = __expf(a - m);
        float ssum = e;
        ssum += __shfl_xor(ssum, 8, 64);
        ssum += __shfl_xor(ssum, 16, 64);
        ssum += __shfl_xor(ssum, 32, 64);
        sm[b * 64 + tid] = e / ssum;       // layout [b][f*8+g]
    }
}

// K4: out[g,b,o,t] = sum_f sm[f,g,b]*selu(conv[f,b,o,t]), conv recomputed.
// grid = B * 4 tiles * 4 og = 512 blocks, block=256. Thread owns (b, 4 t's), 16 o's.
// oi-loop manually unrolled x2 with TWO accumulator arrays: accA's stores are
// only waited on one full iteration later (vmcnt slack ~8), so each wave's
// store drain overlaps the next iteration's conv/selu compute.
__global__ __launch_bounds__(256) void k_out(
        const float* __restrict__ ws, const float* __restrict__ cw,
        const float* __restrict__ cb, float* __restrict__ out) {
    int blk = blockIdx.x;
    int b = blk >> 4;                      // 0..31
    int r = blk & 15;
    int tile = r >> 2;                     // 0..3
    int og = r & 3;                        // 0..3
    int t0 = tile * 1024 + threadIdx.x * 4;
    int lane = threadIdx.x & 63;

    // softmax weights: ONE coalesced lane-load + readlane broadcast -> SGPRs
    const float* smp = ws + SM_OFF + b * 64;
    float myv = smp[lane];
    float smv[64];
    #pragma unroll
    for (int i = 0; i < 64; ++i)
        smv[i] = __int_as_float(__builtin_amdgcn_readlane(__float_as_int(myv), i));

    // xs windows: xw[f][k] = xs_pad[t0+2+k], k=0..7 (covers 4 outputs, K=5)
    float xw[8][8];
    #pragma unroll
    for (int f = 0; f < 8; ++f) {
        const float* xp = ws + XS_OFF + (size_t)(f * B + b) * XSTRIDE + t0;
        float4 q0 = *(const float4*)(xp);
        float4 q1 = *(const float4*)(xp + 4);
        float4 q2 = *(const float4*)(xp + 8);
        xw[f][0] = q0.z; xw[f][1] = q0.w;
        xw[f][2] = q1.x; xw[f][3] = q1.y; xw[f][4] = q1.z; xw[f][5] = q1.w;
        xw[f][6] = q2.x; xw[f][7] = q2.y;
    }

    float accA[8][4], accB[8][4];

#define CONV_BODY(ACC, OIDX)                                                   \
    {                                                                          \
        int o = og * 16 + (OIDX);                                              \
        float w0 = sload(cw + o * 5 + 0), w1 = sload(cw + o * 5 + 1);          \
        float w2 = sload(cw + o * 5 + 2), w3 = sload(cw + o * 5 + 3);          \
        float w4 = sload(cw + o * 5 + 4);                                      \
        float bv = sload(cb + o);                                              \
        _Pragma("unroll")                                                      \
        for (int g = 0; g < 8; ++g)                                            \
            _Pragma("unroll")                                                  \
            for (int dt = 0; dt < 4; ++dt) ACC[g][dt] = 0.0f;                  \
        _Pragma("unroll")                                                      \
        for (int f = 0; f < 8; ++f) {                                          \
            float cv[4];                                                       \
            _Pragma("unroll")                                                  \
            for (int dt = 0; dt < 4; ++dt) {                                   \
                float c = bv + w0 * xw[f][dt] + w1 * xw[f][dt + 1]             \
                        + w2 * xw[f][dt + 2] + w3 * xw[f][dt + 3]              \
                        + w4 * xw[f][dt + 4];                                  \
                cv[dt] = selu_f(c);                                            \
            }                                                                  \
            _Pragma("unroll")                                                  \
            for (int g = 0; g < 8; ++g) {                                      \
                float s = smv[f * 8 + g];                                      \
                _Pragma("unroll")                                              \
                for (int dt = 0; dt < 4; ++dt) ACC[g][dt] += s * cv[dt];       \
            }                                                                  \
        }                                                                      \
        _Pragma("unroll")                                                      \
        for (int g = 0; g < 8; ++g) {                                          \
            float4 o4 = make_float4(ACC[g][0], ACC[g][1], ACC[g][2], ACC[g][3]);\
            *(float4*)(out + ((size_t)(g * B + b) * O + o) * T + t0) = o4;     \
        }                                                                      \
    }

    #pragma unroll 1
    for (int op = 0; op < 8; ++op) {
        CONV_BODY(accA, op * 2 + 0);
        CONV_BODY(accB, op * 2 + 1);
    }
#undef CONV_BODY
}

extern "C" void kernel_launch(void* const* d_in, const int* in_sizes, int n_in,
                              void* d_out, int out_size, void* d_ws, size_t ws_size,
                              hipStream_t stream) {
    const float* x      = (const float*)d_in[0];
    const float* conv_w = (const float*)d_in[1];
    const float* conv_b = (const float*)d_in[2];
    const float* se_w1  = (const float*)d_in[3];
    const float* se_b1  = (const float*)d_in[4];
    const float* se_w2  = (const float*)d_in[5];
    const float* se_b2  = (const float*)d_in[6];
    const float* attn_w = (const float*)d_in[7];
    float* out = (float*)d_out;
    float* ws  = (float*)d_ws;

    k_xs_mean<<<V * B, 512, 0, stream>>>(x, conv_w, conv_b, ws, ws + S_OFF);
    k_se_sm<<<B, 512, 0, stream>>>(ws + S_OFF, se_w1, se_b1, se_w2, se_b2, attn_w,
                                   ws + SM_OFF);
    k_out<<<B * 4 * 4, 256, 0, stream>>>(ws, conv_w, conv_b, out);
}

// Round 7
// 112.743 us; speedup vs baseline: 1.0456x; 1.0089x over previous
//
#include <hip/hip_runtime.h>

// Problem constants
#define V 8
#define B 32
#define CIN 8
#define T 4096
#define O 64
#define K 5
#define H 16

// Padded xs row: [0..3]=0, data at [4..4099], [4100..4103]=0.
// conv(t) = sum_j w[j]*xs[t+j-2] = sum_j w[j]*xs_pad[t+j+2]
#define XSTRIDE 4104

// workspace layout (floats)
#define XS_OFF 0
#define S_OFF  (V*B*XSTRIDE)          // xs: 256 rows * 4104
#define SM_OFF (S_OFF + V*B*O)        // s means; sm follows
// sm size: B*64

__device__ __forceinline__ float selu_f(float x) {
    const float SC = 1.0507009873554805f;
    const float SA = 1.7580993408473766f;  // scale*alpha
    float e = __expf(x);
    float neg = SA * e - SA;               // scale*alpha*(exp(x)-1)
    return x > 0.0f ? SC * x : neg;
}

// K01: xs row build (LDS + global) + per-(row,o) mean of selu(conv).
// grid = V*B (=256), block = 512 (8 waves).
__global__ __launch_bounds__(512) void k_xs_mean(
        const float* __restrict__ x, const float* __restrict__ cw,
        const float* __restrict__ cb, float* __restrict__ ws,
        float* __restrict__ s_out) {
    int row = blockIdx.x;                  // v*B + b
    int tid = threadIdx.x;
    __shared__ float xsh[XSTRIDE];
    const float* xr = x + (size_t)row * CIN * T;
    float* xp = ws + XS_OFF + (size_t)row * XSTRIDE;

    // Phase 1: xs = sum_c x[..c..], 8 t's per thread, float4 I/O.
    {
        int t0 = tid * 8;
        float4 a0 = make_float4(0.f, 0.f, 0.f, 0.f);
        float4 a1 = make_float4(0.f, 0.f, 0.f, 0.f);
        #pragma unroll
        for (int c = 0; c < CIN; ++c) {
            const float4* q = (const float4*)(xr + c * T + t0);
            float4 u = q[0], v2 = q[1];
            a0.x += u.x; a0.y += u.y; a0.z += u.z; a0.w += u.w;
            a1.x += v2.x; a1.y += v2.y; a1.z += v2.z; a1.w += v2.w;
        }
        *(float4*)(&xsh[t0 + 4]) = a0;
        *(float4*)(&xsh[t0 + 8]) = a1;
        *(float4*)(xp + t0 + 4) = a0;
        *(float4*)(xp + t0 + 8) = a1;
        if (tid < 4) {
            xsh[tid] = 0.0f; xsh[4100 + tid] = 0.0f;
            xp[tid] = 0.0f;  xp[4100 + tid] = 0.0f;
        }
    }
    __syncthreads();

    // Phase 2: mean_t selu(conv). lane = o (broadcast LDS reads), wave = t-chunk.
    int wave = tid >> 6;
    int lane = tid & 63;                   // = o
    float w0 = cw[lane * 5 + 0], w1 = cw[lane * 5 + 1], w2 = cw[lane * 5 + 2];
    float w3 = cw[lane * 5 + 3], w4 = cw[lane * 5 + 4];
    float bv = cb[lane];
    int c0 = wave * 512;
    float a0 = xsh[c0 + 2], a1 = xsh[c0 + 3], a2 = xsh[c0 + 4], a3 = xsh[c0 + 5];
    float acc = 0.0f;
    #pragma unroll 8
    for (int t = c0; t < c0 + 512; ++t) {
        float a4 = xsh[t + 6];
        float cv = bv + w0 * a0 + w1 * a1 + w2 * a2 + w3 * a3 + w4 * a4;
        acc += selu_f(cv);
        a0 = a1; a1 = a2; a2 = a3; a3 = a4;
    }
    __shared__ float part[8][64];
    part[wave][lane] = acc;
    __syncthreads();
    if (tid < 64) {
        float tot = 0.0f;
        #pragma unroll
        for (int w = 0; w < 8; ++w) tot += part[w][tid];
        s_out[row * 64 + tid] = tot * (1.0f / (float)T);
    }
}

// K23: SE MLP -> gate -> compressed -> af/at -> softmax sm.
// grid = B (=32), block = 512: wave = v, lane = o.
__global__ __launch_bounds__(512) void k_se_sm(
        const float* __restrict__ s_in, const float* __restrict__ w1,
        const float* __restrict__ b1, const float* __restrict__ w2,
        const float* __restrict__ b2, const float* __restrict__ awv,
        float* __restrict__ sm) {
    int b = blockIdx.x;
    int tid = threadIdx.x;
    int v = tid >> 6;
    int o = tid & 63;
    __shared__ float ssh[8][64];
    __shared__ float hsh[8][16];
    __shared__ float afs[8], ats[8];
    float so = s_in[(v * B + b) * 64 + o];
    ssh[v][o] = so;
    __syncthreads();
    if (o < 16) {
        float hv = b1[v * 16 + o];
        #pragma unroll
        for (int j = 0; j < 64; ++j) hv += ssh[v][j] * w1[(v * 16 + o) * 64 + j];
        hsh[v][o] = fmaxf(hv, 0.0f);
    }
    __syncthreads();
    float gv = b2[v * 64 + o];
    #pragma unroll
    for (int j = 0; j < 16; ++j) gv += hsh[v][j] * w2[(v * 64 + o) * 16 + j];
    float gate = 1.0f / (1.0f + __expf(-gv));
    float comp = so * gate;
    float pf = comp * awv[o];
    float pt = comp * awv[64 + o];
    #pragma unroll
    for (int m = 32; m >= 1; m >>= 1) {
        pf += __shfl_xor(pf, m, 64);
        pt += __shfl_xor(pt, m, 64);
    }
    if (o == 0) { afs[v] = pf; ats[v] = pt; }
    __syncthreads();
    if (tid < 64) {
        int f = tid >> 3, g = tid & 7;
        float a = selu_f(afs[f] + ats[g]);
        float m = a;
        m = fmaxf(m, __shfl_xor(m, 8, 64));
        m = fmaxf(m, __shfl_xor(m, 16, 64));
        m = fmaxf(m, __shfl_xor(m, 32, 64));
        float e = __expf(a - m);
        float ssum = e;
        ssum += __shfl_xor(ssum, 8, 64);
        ssum += __shfl_xor(ssum, 16, 64);
        ssum += __shfl_xor(ssum, 32, 64);
        sm[b * 64 + tid] = e / ssum;       // layout [b][f*8+g]
    }
}

// K4: out[g,b,o,t] = sum_f sm[f,g,b]*selu(conv[f,b,o,t]), conv recomputed.
// grid = B * 4 tiles * 4 og = 512 blocks, block=256. Thread owns (b, 4 t's), 16 o's.
// CRITICAL: weights are read via PLAIN uniform loads (o is block-uniform ->
// compiler emits s_load, which waits on lgkmcnt). NO vmem loads in the loop:
// a vmem load + readfirstlane would force s_waitcnt vmcnt(0), and vmcnt is
// FIFO, so it would drain ALL outstanding stores every iteration (the R2-R6
// plateau). Dual accumulators give the register-reuse waits vmcnt slack.
__global__ __launch_bounds__(256) void k_out(
        const float* __restrict__ ws, const float* __restrict__ cw,
        const float* __restrict__ cb, float* __restrict__ out) {
    int blk = blockIdx.x;
    int b = blk >> 4;                      // 0..31
    int r = blk & 15;
    int tile = r >> 2;                     // 0..3
    int og = r & 3;                        // 0..3
    int t0 = tile * 1024 + threadIdx.x * 4;
    int lane = threadIdx.x & 63;

    // softmax weights: ONE coalesced lane-load + readlane broadcast -> SGPRs
    const float* smp = ws + SM_OFF + b * 64;
    float myv = smp[lane];
    float smv[64];
    #pragma unroll
    for (int i = 0; i < 64; ++i)
        smv[i] = __int_as_float(__builtin_amdgcn_readlane(__float_as_int(myv), i));

    // xs windows: xw[f][k] = xs_pad[t0+2+k], k=0..7 (covers 4 outputs, K=5)
    float xw[8][8];
    #pragma unroll
    for (int f = 0; f < 8; ++f) {
        const float* xp = ws + XS_OFF + (size_t)(f * B + b) * XSTRIDE + t0;
        float4 q0 = *(const float4*)(xp);
        float4 q1 = *(const float4*)(xp + 4);
        float4 q2 = *(const float4*)(xp + 8);
        xw[f][0] = q0.z; xw[f][1] = q0.w;
        xw[f][2] = q1.x; xw[f][3] = q1.y; xw[f][4] = q1.z; xw[f][5] = q1.w;
        xw[f][6] = q2.x; xw[f][7] = q2.y;
    }

    float accA[8][4], accB[8][4];

#define CONV_BODY(ACC, OIDX)                                                   \
    {                                                                          \
        int o = og * 16 + (OIDX);                                              \
        float w0 = cw[o * 5 + 0], w1 = cw[o * 5 + 1];                          \
        float w2 = cw[o * 5 + 2], w3 = cw[o * 5 + 3];                          \
        float w4 = cw[o * 5 + 4];                                              \
        float bv = cb[o];                                                      \
        _Pragma("unroll")                                                      \
        for (int g = 0; g < 8; ++g)                                            \
            _Pragma("unroll")                                                  \
            for (int dt = 0; dt < 4; ++dt) ACC[g][dt] = 0.0f;                  \
        _Pragma("unroll")                                                      \
        for (int f = 0; f < 8; ++f) {                                          \
            float cv[4];                                                       \
            _Pragma("unroll")                                                  \
            for (int dt = 0; dt < 4; ++dt) {                                   \
                float c = bv + w0 * xw[f][dt] + w1 * xw[f][dt + 1]             \
                        + w2 * xw[f][dt + 2] + w3 * xw[f][dt + 3]              \
                        + w4 * xw[f][dt + 4];                                  \
                cv[dt] = selu_f(c);                                            \
            }                                                                  \
            _Pragma("unroll")                                                  \
            for (int g = 0; g < 8; ++g) {                                      \
                float s = smv[f * 8 + g];                                      \
                _Pragma("unroll")                                              \
                for (int dt = 0; dt < 4; ++dt) ACC[g][dt] += s * cv[dt];       \
            }                                                                  \
        }                                                                      \
        _Pragma("unroll")                                                      \
        for (int g = 0; g < 8; ++g) {                                          \
            float4 o4 = make_float4(ACC[g][0], ACC[g][1], ACC[g][2], ACC[g][3]);\
            *(float4*)(out + ((size_t)(g * B + b) * O + o) * T + t0) = o4;     \
        }                                                                      \
    }

    #pragma unroll 1
    for (int op = 0; op < 8; ++op) {
        CONV_BODY(accA, op * 2 + 0);
        CONV_BODY(accB, op * 2 + 1);
    }
#undef CONV_BODY
}

extern "C" void kernel_launch(void* const* d_in, const int* in_sizes, int n_in,
                              void* d_out, int out_size, void* d_ws, size_t ws_size,
                              hipStream_t stream) {
    const float* x      = (const float*)d_in[0];
    const float* conv_w = (const float*)d_in[1];
    const float* conv_b = (const float*)d_in[2];
    const float* se_w1  = (const float*)d_in[3];
    const float* se_b1  = (const float*)d_in[4];
    const float* se_w2  = (const float*)d_in[5];
    const float* se_b2  = (const float*)d_in[6];
    const float* attn_w = (const float*)d_in[7];
    float* out = (float*)d_out;
    float* ws  = (float*)d_ws;

    k_xs_mean<<<V * B, 512, 0, stream>>>(x, conv_w, conv_b, ws, ws + S_OFF);
    k_se_sm<<<B, 512, 0, stream>>>(ws + S_OFF, se_w1, se_b1, se_w2, se_b2, attn_w,
                                   ws + SM_OFF);
    k_out<<<B * 4 * 4, 256, 0, stream>>>(ws, conv_w, conv_b, out);
}